// Round 16
// baseline (103.636 us; speedup 1.0000x reference)
//
#include <hip/hip_runtime.h>
#include <math.h>

#define BINS 10
#define BLOCK 256
#define WAVES (BLOCK / 64)
#define NBLK 2048

// d_ws layout: gsum[10] u64 (bce fixed-point 2^-20) | gcnt[10] u64 | ctr u64
#define WS_U64S (BINS + BINS + 1)

// ---------------------------------------------------------------------------
// Fused single kernel. R6-R14 lesson: wall ~48us is INVARIANT across DS-
// atomic / register-hist / prefetch-depth / LDS-DMA structures while no pipe
// exceeds 43% -> delivered-BW-bound (~3.5 TB/s for this 50% L3-hit stream).
// This round: pure-streaming shape (dual independent streams/thread for max
// ILP), fused finalization via global fixed-point u64 atomics + last-block
// pattern (deterministic: integer adds commute exactly). d_ws zeroed by
// hipMemsetAsync in kernel_launch (captured in the graph, replayed).
// ---------------------------------------------------------------------------

__global__ __launch_bounds__(BLOCK) void ghm_fused(
        const float4* __restrict__ x4, const float4* __restrict__ t4,
        const float* __restrict__ xs, const float* __restrict__ ts,
        unsigned long long* __restrict__ ws, float* __restrict__ out,
        int nvec, int total, float Nf, double inv_total) {
    const int tid  = threadIdx.x;
    const int wid  = tid >> 6;
    const int lane = tid & 63;

    const float L2E    = 1.44269504088896f;   // log2(e)
    const float LN2    = 0.69314718055995f;   // ln(2)

    float sm[BINS];
#pragma unroll
    for (int b = 0; b < BINS; ++b) sm[b] = 0.0f;
    unsigned int cnt[BINS];
#pragma unroll
    for (int b = 0; b < BINS; ++b) cnt[b] = 0u;
    unsigned long long pc = 0ull;             // packed 6-bit per-bin counts

    auto proc = [&](float xv, float tv) {
        float e   = __builtin_amdgcn_exp2f(-L2E * __builtin_fabsf(xv)); // e^-|x|
        float ope = 1.0f + e;
        float r   = __builtin_amdgcn_rcpf(ope);           // 1/(1+e)
        float sig = (xv >= 0.0f) ? r : e * r;             // stable sigmoid
        float g   = __builtin_fabsf(sig - tv);            // [0,1]
        int bi = (int)(g * 9.9999f);
        bi = bi > (BINS - 1) ? (BINS - 1) : bi;           // ulp safety clamp
        float l2  = __builtin_amdgcn_logf(ope);           // log2(1+e)
        float bce = __builtin_fmaf(-xv, tv, __builtin_fmaxf(xv, 0.0f));
        bce = __builtin_fmaf(LN2, l2, bce);               // + ln(1+e)
        pc += 1ull << (6 * bi);
#pragma unroll
        for (int b = 0; b < BINS; ++b)                    // static -> registers
            sm[b] += (bi == b) ? bce : 0.0f;
    };
    auto flush = [&]() {
#pragma unroll
        for (int b = 0; b < BINS; ++b)
            cnt[b] += (unsigned int)((pc >> (6 * b)) & 63ull);
        pc = 0ull;
    };

    const int stride = gridDim.x * BLOCK;
    const int gid    = blockIdx.x * BLOCK + tid;
    const int h      = nvec >> 1;

    // dual independent streams: i (low half) and i+h (high half). 8 elems
    // per iter, two fully independent dependency chains -> 2x wave ILP.
    int i = gid;
    while (i < h) {
        // <=7 iters between flushes: 7*8=56 per bin worst case < 64
        for (int k = 0; k < 7 && i < h; ++k, i += stride) {
            float4 Xa = x4[i];     float4 Ta = t4[i];
            float4 Xb = x4[i + h]; float4 Tb = t4[i + h];
            proc(Xa.x, Ta.x); proc(Xb.x, Tb.x);
            proc(Xa.y, Ta.y); proc(Xb.y, Tb.y);
            proc(Xa.z, Ta.z); proc(Xb.z, Tb.z);
            proc(Xa.w, Ta.w); proc(Xb.w, Tb.w);
        }
        flush();
    }
    // leftover float4s (nvec odd) + scalar tail (total%4) — not hit for bench
    for (int j = (h << 1) + gid; j < nvec; j += stride) {
        float4 X = x4[j]; float4 T = t4[j];
        proc(X.x, T.x); proc(X.y, T.y); proc(X.z, T.z); proc(X.w, T.w);
        flush();
    }
    for (int j = nvec * 4 + gid; j < total; j += stride) { proc(xs[j], ts[j]); flush(); }

    // -------- block reduce: wave shuffle -> LDS --------
    __shared__ float        rs[WAVES][BINS];
    __shared__ unsigned int rc[WAVES][BINS];
#pragma unroll
    for (int b = 0; b < BINS; ++b) {
        float        s = sm[b];
        unsigned int c = cnt[b];
#pragma unroll
        for (int off = 32; off > 0; off >>= 1) {
            s += __shfl_down(s, off);
            c += __shfl_down(c, off);
        }
        if (lane == 0) { rs[wid][b] = s; rc[wid][b] = c; }
    }
    __syncthreads();

    // -------- global accumulation: fixed-point u64 atomics (deterministic)
    if (tid < BINS) {
        float        s = 0.0f;
        unsigned int c = 0u;
#pragma unroll
        for (int w = 0; w < WAVES; ++w) { s += rs[w][tid]; c += rc[w][tid]; }
        // block bce-sum -> 2^-20 fixed point (block sums ~<6e4 -> q < 2^37)
        unsigned long long q =
            (unsigned long long)__builtin_fmaf(s, 1048576.0f, 0.5f);
        atomicAdd(&ws[tid], q);                    // gsum[b]
        atomicAdd(&ws[BINS + tid], (unsigned long long)c);  // gcnt[b]
    }
    __syncthreads();

    // -------- last-block finalization --------
    if (tid == 0) {
        __threadfence();                           // release our atomics
        unsigned long long prev = atomicAdd(&ws[2 * BINS], 1ull);
        if (prev == (unsigned long long)(gridDim.x - 1)) {
            __threadfence();                       // acquire all blocks' adds
            float nonempty = 0.0f;
#pragma unroll
            for (int b = 0; b < BINS; ++b)
                nonempty += (ws[BINS + b] > 0ull) ? 1.0f : 0.0f;
            double acc = 0.0;
#pragma unroll
            for (int b = 0; b < BINS; ++b) {
                float bc   = (float)ws[BINS + b];  // reference keeps fp32
                float gd   = fmaxf(bc * nonempty, 1e-6f);
                float beta = Nf / gd;
                acc += (double)beta * ((double)ws[b] * 9.5367431640625e-7);
            }
            out[0] = (float)(acc * inv_total);
        }
    }
}

// ---------------------------------------------------------------------------

extern "C" void kernel_launch(void* const* d_in, const int* in_sizes, int n_in,
                              void* d_out, int out_size, void* d_ws, size_t ws_size,
                              hipStream_t stream) {
    const float* x = (const float*)d_in[0];
    const float* t = (const float*)d_in[1];
    const int total = in_sizes[0];          // 1048576 * 16
    const int nvec  = total / 4;
    const int N     = total / 16;           // x.shape[0] (first dim)

    // zero the 21-u64 accumulator/arrival workspace (captured + replayed)
    hipMemsetAsync(d_ws, 0, WS_U64S * sizeof(unsigned long long), stream);

    ghm_fused<<<NBLK, BLOCK, 0, stream>>>(
        (const float4*)x, (const float4*)t, x, t,
        (unsigned long long*)d_ws, (float*)d_out,
        nvec, total, (float)N, 1.0 / (double)total);
}

// Round 17
// 98.906 us; speedup vs baseline: 1.0478x; 1.0478x over previous
//
#include <hip/hip_runtime.h>
#include <math.h>

#define BINS 10
#define BLOCK 256
#define WAVES (BLOCK / 64)
#define NBLK 2048
#define DEPTH 4

// d_ws layout: gsum[10] u64 (bce fixed-point 2^-20) | gcnt[10] u64 | ctr u64
#define WS_U64S (BINS + BINS + 1)

// ---------------------------------------------------------------------------
// Fused single kernel = R12's main loop (best bench: 39.5us; single
// contiguous stream per array, 4-deep rotating slots) + R16's validated
// last-block finalize (global fixed-point u64 atomics, deterministic;
// d_ws zeroed by captured hipMemsetAsync).
// R16 lesson: dual DISTANT streams per wave halve delivered BW (0.52 vs
// 1.4 TB/s) -> keep one stream; ILP comes from the 4-elem float4 body.
// ---------------------------------------------------------------------------

__global__ __launch_bounds__(BLOCK) void ghm_fused(
        const float4* __restrict__ x4, const float4* __restrict__ t4,
        const float* __restrict__ xs, const float* __restrict__ ts,
        unsigned long long* __restrict__ ws, float* __restrict__ out,
        int nvec, int total, float Nf, double inv_total) {
    const int tid  = threadIdx.x;
    const int wid  = tid >> 6;
    const int lane = tid & 63;

    const float L2E    = 1.44269504088896f;   // log2(e)
    const float LN2    = 0.69314718055995f;   // ln(2)
    const float QSCALE = 1048576.0f;          // 2^20 fixed point

    float        sm[BINS];
    unsigned int cnt[BINS];
#pragma unroll
    for (int b = 0; b < BINS; ++b) { sm[b] = 0.0f; cnt[b] = 0u; }
    unsigned long long pc = 0ull;             // packed 6-bit per-bin counts

    auto proc = [&](float xv, float tv) {
        float e   = __builtin_amdgcn_exp2f(-L2E * __builtin_fabsf(xv)); // e^-|x|
        float ope = 1.0f + e;
        float r   = __builtin_amdgcn_rcpf(ope);           // 1/(1+e)
        float sig = (xv >= 0.0f) ? r : e * r;             // stable sigmoid
        float g   = __builtin_fabsf(sig - tv);            // [0,1]
        int bi = (int)(g * 9.9999f);
        bi = bi > (BINS - 1) ? (BINS - 1) : bi;           // ulp safety clamp
        float l2  = __builtin_amdgcn_logf(ope);           // log2(1+e)
        float bce = __builtin_fmaf(-xv, tv, __builtin_fmaxf(xv, 0.0f));
        bce = __builtin_fmaf(LN2, l2, bce);               // + ln(1+e)
        pc += 1ull << (6 * bi);
#pragma unroll
        for (int b = 0; b < BINS; ++b)                    // static -> registers
            sm[b] += (bi == b) ? bce : 0.0f;
    };
    auto flush = [&]() {
#pragma unroll
        for (int b = 0; b < BINS; ++b)
            cnt[b] += (unsigned int)((pc >> (6 * b)) & 63ull);
        pc = 0ull;
    };

    const int stride = gridDim.x * BLOCK;                 // float4 units
    const int gid    = blockIdx.x * BLOCK + tid;

    // R12 main loop: 4 rotating slots, single contiguous stream per array.
    // Strides/thread for bench shape: 8 -> one steady-state pass + drain.
    // Flush cadence: each slot-compute is 4 elems; flush every full rotation
    // (16 elems) -> packed fields max 16 < 63 between flushes... actually
    // flush once per while-iteration (16 elems) and after drain (16 elems).
    int i = gid;
    if (gid + (DEPTH - 1) * stride < nvec) {
        float4 X0 = x4[i];              float4 T0 = t4[i];
        float4 X1 = x4[i + stride];     float4 T1 = t4[i + stride];
        float4 X2 = x4[i + 2 * stride]; float4 T2 = t4[i + 2 * stride];
        float4 X3 = x4[i + 3 * stride]; float4 T3 = t4[i + 3 * stride];
        __builtin_amdgcn_sched_barrier(0);
        int inext = i + DEPTH * stride;
        while (inext + 3 * stride < nvec) {
            proc(X0.x, T0.x); proc(X0.y, T0.y); proc(X0.z, T0.z); proc(X0.w, T0.w);
            X0 = x4[inext]; T0 = t4[inext]; inext += stride;
            __builtin_amdgcn_sched_barrier(0);
            proc(X1.x, T1.x); proc(X1.y, T1.y); proc(X1.z, T1.z); proc(X1.w, T1.w);
            X1 = x4[inext]; T1 = t4[inext]; inext += stride;
            __builtin_amdgcn_sched_barrier(0);
            proc(X2.x, T2.x); proc(X2.y, T2.y); proc(X2.z, T2.z); proc(X2.w, T2.w);
            X2 = x4[inext]; T2 = t4[inext]; inext += stride;
            __builtin_amdgcn_sched_barrier(0);
            proc(X3.x, T3.x); proc(X3.y, T3.y); proc(X3.z, T3.z); proc(X3.w, T3.w);
            X3 = x4[inext]; T3 = t4[inext]; inext += stride;
            __builtin_amdgcn_sched_barrier(0);
            flush();                                      // 16 elems/rotation
        }
        proc(X0.x, T0.x); proc(X0.y, T0.y); proc(X0.z, T0.z); proc(X0.w, T0.w);
        proc(X1.x, T1.x); proc(X1.y, T1.y); proc(X1.z, T1.z); proc(X1.w, T1.w);
        proc(X2.x, T2.x); proc(X2.y, T2.y); proc(X2.z, T2.z); proc(X2.w, T2.w);
        proc(X3.x, T3.x); proc(X3.y, T3.y); proc(X3.z, T3.z); proc(X3.w, T3.w);
        flush();
        for (i = inext; i < nvec; i += stride) {
            float4 xa = x4[i]; float4 ta = t4[i];
            proc(xa.x, ta.x); proc(xa.y, ta.y); proc(xa.z, ta.z); proc(xa.w, ta.w);
            flush();
        }
    } else {
        for (; i < nvec; i += stride) {
            float4 xa = x4[i]; float4 ta = t4[i];
            proc(xa.x, ta.x); proc(xa.y, ta.y); proc(xa.z, ta.z); proc(xa.w, ta.w);
            flush();
        }
    }
    // scalar tail (total % 4 != 0; not hit for the bench shape)
    for (int j = nvec * 4 + gid; j < total; j += stride) { proc(xs[j], ts[j]); }
    flush();

    // -------- block reduce: wave shuffle -> LDS --------
    __shared__ float        rs[WAVES][BINS];
    __shared__ unsigned int rc[WAVES][BINS];
#pragma unroll
    for (int b = 0; b < BINS; ++b) {
        float        s = sm[b];
        unsigned int c = cnt[b];
#pragma unroll
        for (int off = 32; off > 0; off >>= 1) {
            s += __shfl_down(s, off);
            c += __shfl_down(c, off);
        }
        if (lane == 0) { rs[wid][b] = s; rc[wid][b] = c; }
    }
    __syncthreads();

    // -------- global accumulation: fixed-point u64 atomics (deterministic)
    if (tid < BINS) {
        float        s = 0.0f;
        unsigned int c = 0u;
#pragma unroll
        for (int w = 0; w < WAVES; ++w) { s += rs[w][tid]; c += rc[w][tid]; }
        // block bce-sum -> 2^-20 fixed point (block sums < ~6e4 -> q < 2^37)
        unsigned long long q =
            (unsigned long long)__builtin_fmaf(s, QSCALE, 0.5f);
        atomicAdd(&ws[tid], q);                             // gsum[b]
        atomicAdd(&ws[BINS + tid], (unsigned long long)c);  // gcnt[b]
    }
    __syncthreads();

    // -------- last-block finalization (validated R16: absmax 0.0) --------
    if (tid == 0) {
        __threadfence();                           // release our atomics
        unsigned long long prev = atomicAdd(&ws[2 * BINS], 1ull);
        if (prev == (unsigned long long)(gridDim.x - 1)) {
            __threadfence();                       // acquire all blocks' adds
            float nonempty = 0.0f;
#pragma unroll
            for (int b = 0; b < BINS; ++b)
                nonempty += (ws[BINS + b] > 0ull) ? 1.0f : 0.0f;
            double acc = 0.0;
#pragma unroll
            for (int b = 0; b < BINS; ++b) {
                float bc   = (float)ws[BINS + b];  // reference keeps fp32
                float gd   = fmaxf(bc * nonempty, 1e-6f);
                float beta = Nf / gd;
                acc += (double)beta * ((double)ws[b] * 9.5367431640625e-7);
            }
            out[0] = (float)(acc * inv_total);
        }
    }
}

// ---------------------------------------------------------------------------

extern "C" void kernel_launch(void* const* d_in, const int* in_sizes, int n_in,
                              void* d_out, int out_size, void* d_ws, size_t ws_size,
                              hipStream_t stream) {
    const float* x = (const float*)d_in[0];
    const float* t = (const float*)d_in[1];
    const int total = in_sizes[0];          // 1048576 * 16
    const int nvec  = total / 4;
    const int N     = total / 16;           // x.shape[0] (first dim)

    // zero the 21-u64 accumulator/arrival workspace (captured + replayed)
    hipMemsetAsync(d_ws, 0, WS_U64S * sizeof(unsigned long long), stream);

    ghm_fused<<<NBLK, BLOCK, 0, stream>>>(
        (const float4*)x, (const float4*)t, x, t,
        (unsigned long long*)d_ws, (float*)d_out,
        nvec, total, (float)N, 1.0 / (double)total);
}

// Round 18
// 39.662 us; speedup vs baseline: 2.6130x; 2.4937x over previous
//
#include <hip/hip_runtime.h>
#include <math.h>

#define BINS 10
#define BLOCK 256
#define NBLK 2048
#define DEPTH 4

// ---------------------------------------------------------------------------
// REVERT to R12 (best measured: bench 39.5us). Two kernels; fused last-block
// finalize is REFUTED (R16/R17: ~78us tail from 2048-block threadfence +
// same-address atomic protocol). Pass 1: lean math + packed ds_add_u64/elem,
// 4-deep rotating load slots. Pass 2: tiny reduce (3-5us).
// ---------------------------------------------------------------------------

__global__ __launch_bounds__(BLOCK) void ghm_pass1(
        const float4* __restrict__ x4, const float4* __restrict__ t4,
        const float* __restrict__ xs, const float* __restrict__ ts,
        float* __restrict__ psum, unsigned int* __restrict__ pcnt,
        int nvec, int total) {
    __shared__ unsigned long long hist[BINS * BLOCK];   // 20 KiB
    const int tid = threadIdx.x;
#pragma unroll
    for (int b = 0; b < BINS; ++b) hist[b * BLOCK + tid] = 0ull;
    __syncthreads();

    const float L2E    = 1.44269504088896f;   // log2(e)
    const float LN2    = 0.69314718055995f;   // ln(2)
    const float QSCALE = 1048576.0f;          // 2^20 fixed point
    unsigned long long* __restrict__ mycol = &hist[tid];

    auto proc = [&](float xv, float tv) {
        float e   = __builtin_amdgcn_exp2f(-L2E * __builtin_fabsf(xv)); // e^-|x|
        float ope = 1.0f + e;
        float r   = __builtin_amdgcn_rcpf(ope);           // 1/(1+e)
        float sig = (xv >= 0.0f) ? r : e * r;             // stable sigmoid
        float g   = __builtin_fabsf(sig - tv);            // [0,1]
        int bi = (int)(g * 9.9999f);
        bi = bi > (BINS - 1) ? (BINS - 1) : bi;           // ulp safety clamp
        float l2  = __builtin_amdgcn_logf(ope);           // log2(1+e)
        float bce = __builtin_fmaf(-xv, tv, __builtin_fmaxf(xv, 0.0f));
        bce = __builtin_fmaf(LN2, l2, bce);               // + ln(1+e)
        unsigned int q = (unsigned int)__builtin_fmaf(bce, QSCALE, 0.5f);
        atomicAdd(mycol + bi * BLOCK,
                  (1ull << 40) | (unsigned long long)q);  // native ds_add_u64
    };

    const int stride = gridDim.x * BLOCK;                 // in float4 units
    const int gid    = blockIdx.x * BLOCK + tid;

    int i = gid;
    if (gid + (DEPTH - 1) * stride < nvec) {
        // ---- prologue: fill 4 slots (8 loads back-to-back)
        float4 X0 = x4[i];              float4 T0 = t4[i];
        float4 X1 = x4[i + stride];     float4 T1 = t4[i + stride];
        float4 X2 = x4[i + 2 * stride]; float4 T2 = t4[i + 2 * stride];
        float4 X3 = x4[i + 3 * stride]; float4 T3 = t4[i + 3 * stride];
        __builtin_amdgcn_sched_barrier(0);
        // ---- steady state: compute slot, reload slot from DEPTH ahead
        int inext = i + DEPTH * stride;                   // next load index
        while (inext + 3 * stride < nvec) {
            proc(X0.x, T0.x); proc(X0.y, T0.y); proc(X0.z, T0.z); proc(X0.w, T0.w);
            X0 = x4[inext]; T0 = t4[inext]; inext += stride;
            __builtin_amdgcn_sched_barrier(0);
            proc(X1.x, T1.x); proc(X1.y, T1.y); proc(X1.z, T1.z); proc(X1.w, T1.w);
            X1 = x4[inext]; T1 = t4[inext]; inext += stride;
            __builtin_amdgcn_sched_barrier(0);
            proc(X2.x, T2.x); proc(X2.y, T2.y); proc(X2.z, T2.z); proc(X2.w, T2.w);
            X2 = x4[inext]; T2 = t4[inext]; inext += stride;
            __builtin_amdgcn_sched_barrier(0);
            proc(X3.x, T3.x); proc(X3.y, T3.y); proc(X3.z, T3.z); proc(X3.w, T3.w);
            X3 = x4[inext]; T3 = t4[inext]; inext += stride;
            __builtin_amdgcn_sched_barrier(0);
        }
        // ---- drain the 4 live slots
        proc(X0.x, T0.x); proc(X0.y, T0.y); proc(X0.z, T0.z); proc(X0.w, T0.w);
        proc(X1.x, T1.x); proc(X1.y, T1.y); proc(X1.z, T1.z); proc(X1.w, T1.w);
        proc(X2.x, T2.x); proc(X2.y, T2.y); proc(X2.z, T2.z); proc(X2.w, T2.w);
        proc(X3.x, T3.x); proc(X3.y, T3.y); proc(X3.z, T3.z); proc(X3.w, T3.w);
        // ---- leftover strided singles (when strides/thread % DEPTH != 0)
        for (i = inext; i < nvec; i += stride) {
            float4 xa = x4[i]; float4 ta = t4[i];
            proc(xa.x, ta.x); proc(xa.y, ta.y); proc(xa.z, ta.z); proc(xa.w, ta.w);
        }
    } else {
        for (; i < nvec; i += stride) {
            float4 xa = x4[i]; float4 ta = t4[i];
            proc(xa.x, ta.x); proc(xa.y, ta.y); proc(xa.z, ta.z); proc(xa.w, ta.w);
        }
    }
    // scalar tail (not hit for the bench shape)
    for (int j = nvec * 4 + gid; j < total; j += stride)
        proc(xs[j], ts[j]);

    __syncthreads();

    // Block reduce. Field safety: <=8192 elems/block -> count < 2^24 at bit
    // 40; sum <= 8192 * 7.4e6 ~ 6e10 < 2^40. No overflow.
    unsigned long long v[BINS];
#pragma unroll
    for (int b = 0; b < BINS; ++b) v[b] = hist[b * BLOCK + tid];
    __syncthreads();                                    // reads done -> reuse

    const int lane = tid & 63;
    const int wid  = tid >> 6;
#pragma unroll
    for (int b = 0; b < BINS; ++b) {
        unsigned long long s = v[b];
#pragma unroll
        for (int off = 32; off > 0; off >>= 1)
            s += __shfl_down(s, off);
        if (lane == 0) hist[wid * BINS + b] = s;
    }
    __syncthreads();
    if (tid < BINS) {
        unsigned long long tot = 0ull;
#pragma unroll
        for (int w = 0; w < BLOCK / 64; ++w) tot += hist[w * BINS + tid];
        unsigned long long sum_fp = tot & ((1ull << 40) - 1ull);
        unsigned int       cntv   = (unsigned int)(tot >> 40);
        psum[(size_t)blockIdx.x * BINS + tid] =
            (float)((double)sum_fp * 9.5367431640625e-7);   // * 2^-20
        pcnt[(size_t)blockIdx.x * BINS + tid] = cntv;
    }
}

// ---------------------------------------------------------------------------
// Pass 2: strided sweep over partials, wave+LDS reduce, fp32 beta math
// exactly as the reference, final scalar.
// ---------------------------------------------------------------------------

__global__ __launch_bounds__(BLOCK) void ghm_pass2(
        const float* __restrict__ psum, const unsigned int* __restrict__ pcnt,
        float* __restrict__ out, int nblocks, float Nf, double inv_total) {
    double       s[BINS];
    unsigned int c[BINS];
#pragma unroll
    for (int b = 0; b < BINS; ++b) { s[b] = 0.0; c[b] = 0u; }

    for (int i = threadIdx.x; i < nblocks; i += BLOCK) {
#pragma unroll
        for (int b = 0; b < BINS; ++b) {
            s[b] += (double)psum[(size_t)i * BINS + b];
            c[b] += pcnt[(size_t)i * BINS + b];
        }
    }

    __shared__ double       ls[BLOCK / 64][BINS];
    __shared__ unsigned int lc[BLOCK / 64][BINS];
    const int lane = threadIdx.x & 63;
    const int wid  = threadIdx.x >> 6;
#pragma unroll
    for (int b = 0; b < BINS; ++b) {
        double       sb = s[b];
        unsigned int cb = c[b];
#pragma unroll
        for (int off = 32; off > 0; off >>= 1) {
            sb += __shfl_down(sb, off);
            cb += __shfl_down(cb, off);
        }
        if (lane == 0) { ls[wid][b] = sb; lc[wid][b] = cb; }
    }
    __syncthreads();

    if (threadIdx.x == 0) {
        double             bin_sum[BINS];
        unsigned long long bin_cnt[BINS];
#pragma unroll
        for (int b = 0; b < BINS; ++b) {
            double ts = 0.0;
            unsigned long long tc = 0;
#pragma unroll
            for (int w = 0; w < BLOCK / 64; ++w) { ts += ls[w][b]; tc += lc[w][b]; }
            bin_sum[b] = ts;
            bin_cnt[b] = tc;
        }
        float nonempty = 0.0f;
#pragma unroll
        for (int b = 0; b < BINS; ++b) nonempty += (bin_cnt[b] > 0) ? 1.0f : 0.0f;
        double acc = 0.0;
#pragma unroll
        for (int b = 0; b < BINS; ++b) {
            float bc   = (float)bin_cnt[b];            // reference keeps fp32
            float gd   = fmaxf(bc * nonempty, 1e-6f);
            float beta = Nf / gd;
            acc += (double)beta * bin_sum[b];
        }
        out[0] = (float)(acc * inv_total);
    }
}

// ---------------------------------------------------------------------------

extern "C" void kernel_launch(void* const* d_in, const int* in_sizes, int n_in,
                              void* d_out, int out_size, void* d_ws, size_t ws_size,
                              hipStream_t stream) {
    const float* x = (const float*)d_in[0];
    const float* t = (const float*)d_in[1];
    const int total = in_sizes[0];          // 1048576 * 16
    const int nvec  = total / 4;
    const int N     = total / 16;           // x.shape[0] (first dim)

    int nblocks = NBLK;
    size_t per_block = (size_t)BINS * (sizeof(float) + sizeof(unsigned int));
    if ((size_t)nblocks * per_block > ws_size) {
        nblocks = (int)(ws_size / per_block);
        if (nblocks < 1) nblocks = 1;
    }

    float*        psum = (float*)d_ws;
    unsigned int* pcnt = (unsigned int*)((char*)d_ws +
                          (size_t)nblocks * BINS * sizeof(float));

    ghm_pass1<<<nblocks, BLOCK, 0, stream>>>(
        (const float4*)x, (const float4*)t, x, t, psum, pcnt, nvec, total);
    ghm_pass2<<<1, BLOCK, 0, stream>>>(
        psum, pcnt, (float*)d_out, nblocks, (float)N, 1.0 / (double)total);
}